// Round 1
// baseline (308.609 us; speedup 1.0000x reference)
//
#include <hip/hip_runtime.h>
#include <hip/hip_bf16.h>
#include <stdint.h>
#include <stddef.h>

// ---------------------------------------------------------------------------
// CausalAttention: x[2,2048,1024] f32, W_QKV[3072,1024], W_O[1024,1024]
// qkv = x @ W_QKV^T ; per-head causal attention ; out = att @ W_O^T
// All matmuls in bf16 MFMA (16x16x32), fp32 accumulate.
// ---------------------------------------------------------------------------

typedef __attribute__((ext_vector_type(8))) __bf16 bf16x8;
typedef __attribute__((ext_vector_type(4))) float  f32x4;

#define AS1(p) ((__attribute__((address_space(1))) void*)(p))
#define AS3(p) ((__attribute__((address_space(3))) void*)(p))

static constexpr int Tq   = 2048;
static constexpr int Cd   = 1024;
static constexpr int Hh   = 16;
static constexpr int Dk   = 64;
static constexpr int Mrows = 2 * Tq;   // 4096

// ---------------------------------------------------------------------------
// f32 -> bf16 cast, vectorized 8/thread
// ---------------------------------------------------------------------------
__global__ __launch_bounds__(256) void cvt_bf16_kernel(const float* __restrict__ in,
                                                       __bf16* __restrict__ out, int n8)
{
    int idx    = blockIdx.x * blockDim.x + threadIdx.x;
    int stride = gridDim.x * blockDim.x;
    for (int i = idx; i < n8; i += stride) {
        f32x4 a = ((const f32x4*)in)[i * 2 + 0];
        f32x4 b = ((const f32x4*)in)[i * 2 + 1];
        bf16x8 o;
#pragma unroll
        for (int j = 0; j < 4; ++j) { o[j] = (__bf16)a[j]; o[4 + j] = (__bf16)b[j]; }
        ((bf16x8*)out)[i] = o;
    }
}

// ---------------------------------------------------------------------------
// GEMM, B^T layout: C[m][n] = sum_k A[m*K+k] * B[n*K+k]
// 128x128 tile, BK=64, 256 threads (4 waves, 2x2 of 64x64), m97 structure.
// LDS staged via global_load_lds (linear dest) with XOR-swizzled SOURCE granule
// (g ^= row&7); fragment ds_read_b128 applies the same swizzle -> ~2-way banks.
// ---------------------------------------------------------------------------
template <bool OUT_BF16>
__global__ __launch_bounds__(256) void gemm_bt_kernel(const __bf16* __restrict__ A,
                                                      const __bf16* __restrict__ Bm,
                                                      float* __restrict__ Cf,
                                                      __bf16* __restrict__ Cb,
                                                      int N, int K)
{
    __shared__ __align__(16) __bf16 As[128 * 64];
    __shared__ __align__(16) __bf16 Bs[128 * 64];

    const int tid = threadIdx.x;
    const int l   = tid & 63;
    const int w   = tid >> 6;
    const int wr  = w >> 1, wc = w & 1;
    const int lo  = l & 15, hi = l >> 4;
    const int m0  = blockIdx.x * 128;
    const int n0  = blockIdx.y * 128;

    f32x4 acc[4][4] = {};

    for (int kk = 0; kk < K; kk += 64) {
#pragma unroll
        for (int i = 0; i < 4; ++i) {
            int s   = i * 256 + tid;
            int row = s >> 3;
            int gg  = (s & 7) ^ (row & 7);            // inverse-swizzled source granule
            const __bf16* srcA = A  + (size_t)(m0 + row) * K + kk + gg * 8;
            const __bf16* srcB = Bm + (size_t)(n0 + row) * K + kk + gg * 8;
            __builtin_amdgcn_global_load_lds(AS1(srcA), AS3((char*)As + s * 16), 16, 0, 0);
            __builtin_amdgcn_global_load_lds(AS1(srcB), AS3((char*)Bs + s * 16), 16, 0, 0);
        }
        __syncthreads();

#pragma unroll
        for (int ks = 0; ks < 2; ++ks) {
            bf16x8 af[4], bf[4];
#pragma unroll
            for (int m = 0; m < 4; ++m) {
                int row = wr * 64 + m * 16 + lo;
                int gl  = (ks * 4 + hi) ^ (row & 7);  // swizzled read granule
                af[m] = *(const bf16x8*)((const char*)As + row * 128 + gl * 16);
            }
#pragma unroll
            for (int n = 0; n < 4; ++n) {
                int row = wc * 64 + n * 16 + lo;
                int gl  = (ks * 4 + hi) ^ (row & 7);
                bf[n] = *(const bf16x8*)((const char*)Bs + row * 128 + gl * 16);
            }
#pragma unroll
            for (int m = 0; m < 4; ++m)
#pragma unroll
                for (int n = 0; n < 4; ++n)
                    acc[m][n] = __builtin_amdgcn_mfma_f32_16x16x32_bf16(af[m], bf[n], acc[m][n], 0, 0, 0);
        }
        __syncthreads();
    }

    // epilogue: C/D layout col = lane&15, row = (lane>>4)*4 + r   [m89/m91]
#pragma unroll
    for (int m = 0; m < 4; ++m)
#pragma unroll
        for (int n = 0; n < 4; ++n)
#pragma unroll
            for (int r = 0; r < 4; ++r) {
                int row = m0 + wr * 64 + m * 16 + hi * 4 + r;
                int col = n0 + wc * 64 + n * 16 + lo;
                if (OUT_BF16) Cb[(size_t)row * N + col] = (__bf16)acc[m][n][r];
                else          Cf[(size_t)row * N + col] = acc[m][n][r];
            }
}

// ---------------------------------------------------------------------------
// Flash-style causal attention.
// Grid: B*H*(T/64) blocks, 256 threads (4 waves x 16 q-rows). KVBLK=64.
// qkv is bf16 [4096][3072]; Q pre-scaled by 1/8 (exact exponent shift in bf16).
// K staged swizzled via global_load_lds; V staged transposed (swizzled rows);
// P goes through per-wave swizzled LDS tile to become the PV A-operand.
// Mask value -1e30 => expf underflow to exact 0, no NaN paths.
// ---------------------------------------------------------------------------
__global__ __launch_bounds__(256) void attn_kernel(const __bf16* __restrict__ qkv,
                                                   __bf16* __restrict__ att)
{
    __shared__ __align__(16) __bf16 Ks[64 * 64];
    __shared__ __align__(16) __bf16 VTs[64 * 64];
    __shared__ __align__(16) __bf16 Ps[4][16 * 64];

    const int tid = threadIdx.x;
    const int l   = tid & 63;
    const int w   = tid >> 6;
    const int lo  = l & 15, hi = l >> 4;

    const int NQ  = Tq / 64;             // 32
    const int bid = blockIdx.x;
    const int b   = bid / (Hh * NQ);
    const int h   = (bid / NQ) % Hh;
    const int qt  = bid % NQ;
    const int q0  = qt * 64;

    // Q fragments (A-operand: row = lane&15, k = ks*32 + (lane>>4)*8 + j)
    bf16x8 qf[2];
    {
        int qrow = q0 + w * 16 + lo;
        const __bf16* Qp = qkv + (size_t)(b * Tq + qrow) * 3072 + h * 64 + hi * 8;
#pragma unroll
        for (int s = 0; s < 2; ++s) {
            bf16x8 v = *(const bf16x8*)(Qp + s * 32);
#pragma unroll
            for (int j = 0; j < 8; ++j) v[j] = (__bf16)((float)v[j] * 0.125f);
            qf[s] = v;
        }
    }

    f32x4 o[4] = {};
    float mrow[4], lsum[4];
#pragma unroll
    for (int r = 0; r < 4; ++r) { mrow[r] = -1e30f; lsum[r] = 0.f; }

    for (int k0 = 0; k0 <= q0; k0 += 64) {
        // --- stage K (64x64, swizzled source granule, linear LDS dest) ---
#pragma unroll
        for (int i = 0; i < 2; ++i) {
            int s   = i * 256 + tid;
            int row = s >> 3;
            int gg  = (s & 7) ^ (row & 7);
            const __bf16* srcK = qkv + (size_t)(b * Tq + k0 + row) * 3072 + 1024 + h * 64 + gg * 8;
            __builtin_amdgcn_global_load_lds(AS1(srcK), AS3((char*)Ks + s * 16), 16, 0, 0);
        }
        // --- stage V transposed: VTs[d][k], rows XOR-swizzled ---
#pragma unroll
        for (int i = 0; i < 2; ++i) {
            int s    = i * 256 + tid;
            int krow = s >> 3;
            int gg   = s & 7;
            bf16x8 v = *(const bf16x8*)(qkv + (size_t)(b * Tq + k0 + krow) * 3072 + 2048 + h * 64 + gg * 8);
#pragma unroll
            for (int j = 0; j < 8; ++j) {
                int d    = gg * 8 + j;
                int byte = d * 128 + ((krow * 2) ^ ((d & 7) << 4));
                *(__bf16*)((char*)VTs + byte) = v[j];
            }
        }
        __syncthreads();

        // --- S = (Q/8) K^T ---
        f32x4 sf[4] = {};
#pragma unroll
        for (int ks = 0; ks < 2; ++ks)
#pragma unroll
            for (int n = 0; n < 4; ++n) {
                int row = n * 16 + lo;
                int gl  = (ks * 4 + hi) ^ (row & 7);
                bf16x8 kf = *(const bf16x8*)((const char*)Ks + row * 128 + gl * 16);
                sf[n] = __builtin_amdgcn_mfma_f32_16x16x32_bf16(qf[ks], kf, sf[n], 0, 0, 0);
            }

        // --- causal mask ---
        const int qg = q0 + w * 16 + hi * 4;
#pragma unroll
        for (int n = 0; n < 4; ++n) {
            int kg = k0 + n * 16 + lo;
#pragma unroll
            for (int r = 0; r < 4; ++r)
                if (kg > qg + r) sf[n][r] = -1e30f;
        }

        // --- online softmax (row stats within each 16-lane group) ---
#pragma unroll
        for (int r = 0; r < 4; ++r) {
            float mx = fmaxf(fmaxf(sf[0][r], sf[1][r]), fmaxf(sf[2][r], sf[3][r]));
            mx = fmaxf(mx, __shfl_xor(mx, 1));
            mx = fmaxf(mx, __shfl_xor(mx, 2));
            mx = fmaxf(mx, __shfl_xor(mx, 4));
            mx = fmaxf(mx, __shfl_xor(mx, 8));
            float mnew = fmaxf(mrow[r], mx);
            float fac  = __expf(mrow[r] - mnew);
            mrow[r] = mnew;

            float rs = 0.f;
            const int q_loc = hi * 4 + r;
#pragma unroll
            for (int n = 0; n < 4; ++n) {
                float  pv = __expf(sf[n][r] - mnew);
                __bf16 pb = (__bf16)pv;
                rs += (float)pb;                       // consistent with PV numerator
                int k    = n * 16 + lo;
                int byte = q_loc * 128 + ((k * 2) ^ ((q_loc & 7) << 4));
                *(__bf16*)((char*)Ps[w] + byte) = pb;
            }
            rs += __shfl_xor(rs, 1);
            rs += __shfl_xor(rs, 2);
            rs += __shfl_xor(rs, 4);
            rs += __shfl_xor(rs, 8);
            lsum[r] = lsum[r] * fac + rs;
#pragma unroll
            for (int nd = 0; nd < 4; ++nd) o[nd][r] *= fac;
        }

        // --- O += P V ---
#pragma unroll
        for (int ks = 0; ks < 2; ++ks) {
            int glq = (ks * 4 + hi) ^ (lo & 7);
            bf16x8 pa = *(const bf16x8*)((const char*)Ps[w] + lo * 128 + glq * 16);
#pragma unroll
            for (int nd = 0; nd < 4; ++nd) {
                int row = nd * 16 + lo;
                int gl  = (ks * 4 + hi) ^ (row & 7);
                bf16x8 vb = *(const bf16x8*)((const char*)VTs + row * 128 + gl * 16);
                o[nd] = __builtin_amdgcn_mfma_f32_16x16x32_bf16(pa, vb, o[nd], 0, 0, 0);
            }
        }
        __syncthreads();
    }

    // --- normalize + write att (bf16 [4096][1024]) ---
#pragma unroll
    for (int nd = 0; nd < 4; ++nd)
#pragma unroll
        for (int r = 0; r < 4; ++r) {
            float val = o[nd][r] / lsum[r];
            int row = b * Tq + q0 + w * 16 + hi * 4 + r;
            int col = h * 64 + nd * 16 + lo;
            att[(size_t)row * Cd + col] = (__bf16)val;
        }
}

// ---------------------------------------------------------------------------
// Launch
// ---------------------------------------------------------------------------
extern "C" void kernel_launch(void* const* d_in, const int* in_sizes, int n_in,
                              void* d_out, int out_size, void* d_ws, size_t ws_size,
                              hipStream_t stream)
{
    (void)in_sizes; (void)n_in; (void)out_size; (void)ws_size;

    const float* x    = (const float*)d_in[0];
    const float* Wqkv = (const float*)d_in[1];
    const float* Wo   = (const float*)d_in[2];
    float*       out  = (float*)d_out;

    char* ws = (char*)d_ws;
    __bf16* xb    = (__bf16*)(ws);                         //  8 MB: [4096][1024]
    __bf16* wqkvb = (__bf16*)(ws + (size_t)8  * 1024 * 1024); //  6 MB: [3072][1024]
    __bf16* wob   = (__bf16*)(ws + (size_t)14 * 1024 * 1024); //  2 MB: [1024][1024]
    __bf16* qkvb  = (__bf16*)(ws + (size_t)16 * 1024 * 1024); // 24 MB: [4096][3072]
    __bf16* attb  = (__bf16*)(ws + (size_t)40 * 1024 * 1024); //  8 MB: [4096][1024]

    cvt_bf16_kernel<<<2048, 256, 0, stream>>>(x,    xb,    Mrows * Cd / 8);
    cvt_bf16_kernel<<<1536, 256, 0, stream>>>(Wqkv, wqkvb, 3 * Cd * Cd / 8);
    cvt_bf16_kernel<<<512,  256, 0, stream>>>(Wo,   wob,   Cd * Cd / 8);

    dim3 g1(Mrows / 128, 3 * Cd / 128);   // 32 x 24
    gemm_bt_kernel<true><<<g1, 256, 0, stream>>>(xb, wqkvb, nullptr, qkvb, 3 * Cd, Cd);

    attn_kernel<<<2 * Hh * (Tq / 64), 256, 0, stream>>>(qkvb, attb);

    dim3 g2(Mrows / 128, Cd / 128);       // 32 x 8
    gemm_bt_kernel<false><<<g2, 256, 0, stream>>>(attb, wob, out, nullptr, Cd, Cd);
}

// Round 3
// 221.820 us; speedup vs baseline: 1.3913x; 1.3913x over previous
//
#include <hip/hip_runtime.h>
#include <hip/hip_bf16.h>
#include <stdint.h>
#include <stddef.h>

// ---------------------------------------------------------------------------
// CausalAttention: x[2,2048,1024] f32, W_QKV[3072,1024], W_O[1024,1024]
// qkv = x @ W_QKV^T ; per-head causal attention ; out = att @ W_O^T
// All matmuls in bf16 MFMA (16x16x32), fp32 accumulate.
// ---------------------------------------------------------------------------

typedef __attribute__((ext_vector_type(8))) __bf16 bf16x8;
typedef __attribute__((ext_vector_type(4))) float  f32x4;

#define AS1(p) ((__attribute__((address_space(1))) void*)(p))
#define AS3(p) ((__attribute__((address_space(3))) void*)(p))

static constexpr int Tq    = 2048;
static constexpr int Cd    = 1024;
static constexpr int Hh    = 16;
static constexpr int Mrows = 2 * Tq;   // 4096

// ---------------------------------------------------------------------------
// f32 -> bf16 cast, vectorized 8/thread
// ---------------------------------------------------------------------------
__global__ __launch_bounds__(256) void cvt_bf16_kernel(const float* __restrict__ in,
                                                       __bf16* __restrict__ out, int n8)
{
    int idx    = blockIdx.x * blockDim.x + threadIdx.x;
    int stride = gridDim.x * blockDim.x;
    for (int i = idx; i < n8; i += stride) {
        f32x4 a = ((const f32x4*)in)[i * 2 + 0];
        f32x4 b = ((const f32x4*)in)[i * 2 + 1];
        bf16x8 o;
#pragma unroll
        for (int j = 0; j < 4; ++j) { o[j] = (__bf16)a[j]; o[4 + j] = (__bf16)b[j]; }
        ((bf16x8*)out)[i] = o;
    }
}

// ---------------------------------------------------------------------------
// V transpose: qkv[4096][3072] V-part (cols 2048..3071) -> vT[1024][4096]
// vT[hd][r] = qkv[r][2048+hd].  64x64 tiles, LDS stride 65 (2-way banks).
// ---------------------------------------------------------------------------
__global__ __launch_bounds__(256) void transpose_v_kernel(const __bf16* __restrict__ qkv,
                                                          __bf16* __restrict__ vT)
{
    __shared__ __bf16 tile[64][65];
    const int t   = threadIdx.x;
    const int r0  = blockIdx.x * 64;
    const int hd0 = blockIdx.y * 64;

    {
        const int rr = t >> 2, c16 = (t & 3) * 16;
        const __bf16* src = qkv + (size_t)(r0 + rr) * 3072 + 2048 + hd0 + c16;
        bf16x8 a = *(const bf16x8*)(src);
        bf16x8 b = *(const bf16x8*)(src + 8);
#pragma unroll
        for (int j = 0; j < 8; ++j) { tile[rr][c16 + j] = a[j]; tile[rr][c16 + 8 + j] = b[j]; }
    }
    __syncthreads();
    {
        const int hd_loc = t >> 2, rg = (t & 3) * 16;
        bf16x8 a, b;
#pragma unroll
        for (int j = 0; j < 8; ++j) { a[j] = tile[rg + j][hd_loc]; b[j] = tile[rg + 8 + j][hd_loc]; }
        __bf16* dst = vT + (size_t)(hd0 + hd_loc) * Mrows + r0 + rg;
        *(bf16x8*)(dst)     = a;
        *(bf16x8*)(dst + 8) = b;
    }
}

// ---------------------------------------------------------------------------
// GEMM, B^T layout: C[m][n] = sum_k A[m*K+k] * B[n*K+k]
// 128x128 tile, BK=64, 256 threads (4 waves, 2x2 of 64x64), m97 structure.
// ---------------------------------------------------------------------------
template <bool OUT_BF16>
__global__ __launch_bounds__(256) void gemm_bt_kernel(const __bf16* __restrict__ A,
                                                      const __bf16* __restrict__ Bm,
                                                      float* __restrict__ Cf,
                                                      __bf16* __restrict__ Cb,
                                                      int N, int K)
{
    __shared__ __align__(16) __bf16 As[128 * 64];
    __shared__ __align__(16) __bf16 Bs[128 * 64];

    const int tid = threadIdx.x;
    const int l   = tid & 63;
    const int w   = tid >> 6;
    const int wr  = w >> 1, wc = w & 1;
    const int lo  = l & 15, hi = l >> 4;
    const int m0  = blockIdx.x * 128;
    const int n0  = blockIdx.y * 128;

    f32x4 acc[4][4] = {};

    for (int kk = 0; kk < K; kk += 64) {
#pragma unroll
        for (int i = 0; i < 4; ++i) {
            int s   = i * 256 + tid;
            int row = s >> 3;
            int gg  = (s & 7) ^ (row & 7);
            const __bf16* srcA = A  + (size_t)(m0 + row) * K + kk + gg * 8;
            const __bf16* srcB = Bm + (size_t)(n0 + row) * K + kk + gg * 8;
            __builtin_amdgcn_global_load_lds(AS1(srcA), AS3((char*)As + s * 16), 16, 0, 0);
            __builtin_amdgcn_global_load_lds(AS1(srcB), AS3((char*)Bs + s * 16), 16, 0, 0);
        }
        __syncthreads();

#pragma unroll
        for (int ks = 0; ks < 2; ++ks) {
            bf16x8 af[4], bfr[4];
#pragma unroll
            for (int m = 0; m < 4; ++m) {
                int row = wr * 64 + m * 16 + lo;
                int gl  = (ks * 4 + hi) ^ (row & 7);
                af[m] = *(const bf16x8*)((const char*)As + row * 128 + gl * 16);
            }
#pragma unroll
            for (int n = 0; n < 4; ++n) {
                int row = wc * 64 + n * 16 + lo;
                int gl  = (ks * 4 + hi) ^ (row & 7);
                bfr[n] = *(const bf16x8*)((const char*)Bs + row * 128 + gl * 16);
            }
#pragma unroll
            for (int m = 0; m < 4; ++m)
#pragma unroll
                for (int n = 0; n < 4; ++n)
                    acc[m][n] = __builtin_amdgcn_mfma_f32_16x16x32_bf16(af[m], bfr[n], acc[m][n], 0, 0, 0);
        }
        __syncthreads();
    }

#pragma unroll
    for (int m = 0; m < 4; ++m)
#pragma unroll
        for (int n = 0; n < 4; ++n)
#pragma unroll
            for (int r = 0; r < 4; ++r) {
                int row = m0 + wr * 64 + m * 16 + hi * 4 + r;
                int col = n0 + wc * 64 + n * 16 + lo;
                if (OUT_BF16) Cb[(size_t)row * N + col] = (__bf16)acc[m][n][r];
                else          Cf[(size_t)row * N + col] = acc[m][n][r];
            }
}

// ---------------------------------------------------------------------------
// Flash-style causal attention, balanced + double-buffered.
// Grid: 512 blocks (pair index j in 0..15, h, b), 256 threads = 4 waves x 16 q.
// Each block sequentially processes q-tiles {31-j, j} -> exactly 33 k-tile
// iterations per block (perfect balance).
// K staged from qkv; V staged from precomputed vT (both global_load_lds,
// XOR-swizzled source granule + swizzled ds_read_b128 -> conflict-free).
// Double-buffered: stage tile t+1, compute tile t, one barrier per iteration.
// ---------------------------------------------------------------------------
__global__ __launch_bounds__(256) void attn_kernel(const __bf16* __restrict__ qkv,
                                                   const __bf16* __restrict__ vT,
                                                   __bf16* __restrict__ att)
{
    __shared__ __align__(16) __bf16 Ks[2][64 * 64];
    __shared__ __align__(16) __bf16 Vs[2][64 * 64];
    __shared__ __align__(16) __bf16 Ps[4][16 * 64];

    const int tid = threadIdx.x;
    const int l   = tid & 63;
    const int w   = tid >> 6;
    const int lo  = l & 15, hi = l >> 4;

    const int bid = blockIdx.x;
    const int j   = bid & 15;
    const int h   = (bid >> 4) & 15;
    const int b   = bid >> 8;

    const __bf16* Kbase = qkv + (size_t)b * Tq * 3072 + 1024 + h * 64;   // +kr*3072 + d
    const __bf16* Vbase = vT  + (size_t)h * 64 * Mrows + b * Tq;         // +d*4096 + k

    // staging indices (each thread stages 2 granules per tile per buffer)
    const int s0 = tid, s1 = 256 + tid;
    const int row_s0 = s0 >> 3, gg_s0 = (s0 & 7) ^ (row_s0 & 7);
    const int row_s1 = s1 >> 3, gg_s1 = (s1 & 7) ^ (row_s1 & 7);

    const int qts[2] = {31 - j, j};

    for (int p = 0; p < 2; ++p) {
        const int qt = qts[p];
        const int q0 = qt * 64;
        const int nt = qt + 1;

        // Q fragments (A-operand: row = lane&15, k = ks*32 + (lane>>4)*8 + jj)
        bf16x8 qf[2];
        {
            const __bf16* Qp = qkv + (size_t)(b * Tq + q0 + w * 16 + lo) * 3072 + h * 64 + hi * 8;
#pragma unroll
            for (int s = 0; s < 2; ++s) {
                bf16x8 v = *(const bf16x8*)(Qp + s * 32);
#pragma unroll
                for (int jj = 0; jj < 8; ++jj) v[jj] = (__bf16)((float)v[jj] * 0.125f);
                qf[s] = v;
            }
        }

        f32x4 o[4] = {};
        float mrow[4], lsum[4];
#pragma unroll
        for (int r = 0; r < 4; ++r) { mrow[r] = -1e30f; lsum[r] = 0.f; }

        // prologue: stage tile 0 -> buf 0
        {
            const __bf16* kp0 = Kbase + (size_t)row_s0 * 3072 + gg_s0 * 8;
            const __bf16* kp1 = Kbase + (size_t)row_s1 * 3072 + gg_s1 * 8;
            const __bf16* vp0 = Vbase + (size_t)row_s0 * Mrows + gg_s0 * 8;
            const __bf16* vp1 = Vbase + (size_t)row_s1 * Mrows + gg_s1 * 8;
            __builtin_amdgcn_global_load_lds(AS1(kp0), AS3((char*)Ks[0] + s0 * 16), 16, 0, 0);
            __builtin_amdgcn_global_load_lds(AS1(kp1), AS3((char*)Ks[0] + s1 * 16), 16, 0, 0);
            __builtin_amdgcn_global_load_lds(AS1(vp0), AS3((char*)Vs[0] + s0 * 16), 16, 0, 0);
            __builtin_amdgcn_global_load_lds(AS1(vp1), AS3((char*)Vs[0] + s1 * 16), 16, 0, 0);
        }
        __syncthreads();

        int cur = 0;
        for (int t = 0; t < nt; ++t) {
            const int k0 = t * 64;

            // stage next tile into buf cur^1 (overlaps with compute below)
            if (t + 1 < nt) {
                const int kn = k0 + 64;
                const __bf16* kp0 = Kbase + (size_t)(kn + row_s0) * 3072 + gg_s0 * 8;
                const __bf16* kp1 = Kbase + (size_t)(kn + row_s1) * 3072 + gg_s1 * 8;
                const __bf16* vp0 = Vbase + (size_t)row_s0 * Mrows + kn + gg_s0 * 8;
                const __bf16* vp1 = Vbase + (size_t)row_s1 * Mrows + kn + gg_s1 * 8;
                __builtin_amdgcn_global_load_lds(AS1(kp0), AS3((char*)Ks[cur ^ 1] + s0 * 16), 16, 0, 0);
                __builtin_amdgcn_global_load_lds(AS1(kp1), AS3((char*)Ks[cur ^ 1] + s1 * 16), 16, 0, 0);
                __builtin_amdgcn_global_load_lds(AS1(vp0), AS3((char*)Vs[cur ^ 1] + s0 * 16), 16, 0, 0);
                __builtin_amdgcn_global_load_lds(AS1(vp1), AS3((char*)Vs[cur ^ 1] + s1 * 16), 16, 0, 0);
            }

            // --- S = (Q/8) K^T ---
            f32x4 sf[4] = {};
#pragma unroll
            for (int ks = 0; ks < 2; ++ks)
#pragma unroll
                for (int n = 0; n < 4; ++n) {
                    int row = n * 16 + lo;
                    int gl  = (ks * 4 + hi) ^ (row & 7);
                    bf16x8 kf = *(const bf16x8*)((const char*)Ks[cur] + row * 128 + gl * 16);
                    sf[n] = __builtin_amdgcn_mfma_f32_16x16x32_bf16(qf[ks], kf, sf[n], 0, 0, 0);
                }

            // --- causal mask ---
            const int qg = q0 + w * 16 + hi * 4;
#pragma unroll
            for (int n = 0; n < 4; ++n) {
                int kg = k0 + n * 16 + lo;
#pragma unroll
                for (int r = 0; r < 4; ++r)
                    if (kg > qg + r) sf[n][r] = -1e30f;
            }

            // --- online softmax (row stats within each 16-lane group) ---
#pragma unroll
            for (int r = 0; r < 4; ++r) {
                float mx = fmaxf(fmaxf(sf[0][r], sf[1][r]), fmaxf(sf[2][r], sf[3][r]));
                mx = fmaxf(mx, __shfl_xor(mx, 1));
                mx = fmaxf(mx, __shfl_xor(mx, 2));
                mx = fmaxf(mx, __shfl_xor(mx, 4));
                mx = fmaxf(mx, __shfl_xor(mx, 8));
                float mnew = fmaxf(mrow[r], mx);
                float fac  = __expf(mrow[r] - mnew);
                mrow[r] = mnew;

                float rs = 0.f;
                const int q_loc = hi * 4 + r;
#pragma unroll
                for (int n = 0; n < 4; ++n) {
                    float  pv = __expf(sf[n][r] - mnew);
                    __bf16 pb = (__bf16)pv;
                    rs += (float)pb;
                    int k    = n * 16 + lo;
                    int byte = q_loc * 128 + ((k * 2) ^ ((q_loc & 7) << 4));
                    *(__bf16*)((char*)Ps[w] + byte) = pb;
                }
                rs += __shfl_xor(rs, 1);
                rs += __shfl_xor(rs, 2);
                rs += __shfl_xor(rs, 4);
                rs += __shfl_xor(rs, 8);
                lsum[r] = lsum[r] * fac + rs;
#pragma unroll
                for (int nd = 0; nd < 4; ++nd) o[nd][r] *= fac;
            }

            // --- O += P V  (V fragments straight from V^T tile) ---
#pragma unroll
            for (int ks = 0; ks < 2; ++ks) {
                int glq = (ks * 4 + hi) ^ (lo & 7);
                bf16x8 pa = *(const bf16x8*)((const char*)Ps[w] + lo * 128 + glq * 16);
#pragma unroll
                for (int nd = 0; nd < 4; ++nd) {
                    int row = nd * 16 + lo;
                    int gl  = (ks * 4 + hi) ^ (row & 7);
                    bf16x8 vb = *(const bf16x8*)((const char*)Vs[cur] + row * 128 + gl * 16);
                    o[nd] = __builtin_amdgcn_mfma_f32_16x16x32_bf16(pa, vb, o[nd], 0, 0, 0);
                }
            }

            __syncthreads();   // drains vmcnt: buf[cur^1] staged; protects buf reuse
            cur ^= 1;
        }

        // --- normalize + write att (bf16 [4096][1024]) ---
#pragma unroll
        for (int nd = 0; nd < 4; ++nd)
#pragma unroll
            for (int r = 0; r < 4; ++r) {
                float val = o[nd][r] / lsum[r];
                int row = b * Tq + q0 + w * 16 + hi * 4 + r;
                int col = h * 64 + nd * 16 + lo;
                att[(size_t)row * Cd + col] = (__bf16)val;
            }
    }
}

// ---------------------------------------------------------------------------
// Launch
// ---------------------------------------------------------------------------
extern "C" void kernel_launch(void* const* d_in, const int* in_sizes, int n_in,
                              void* d_out, int out_size, void* d_ws, size_t ws_size,
                              hipStream_t stream)
{
    (void)in_sizes; (void)n_in; (void)out_size; (void)ws_size;

    const float* x    = (const float*)d_in[0];
    const float* Wqkv = (const float*)d_in[1];
    const float* Wo   = (const float*)d_in[2];
    float*       out  = (float*)d_out;

    char* ws = (char*)d_ws;
    __bf16* xb    = (__bf16*)(ws);                            //  8 MB: [4096][1024]
    __bf16* wqkvb = (__bf16*)(ws + (size_t)8  * 1024 * 1024); //  6 MB: [3072][1024]
    __bf16* wob   = (__bf16*)(ws + (size_t)14 * 1024 * 1024); //  2 MB: [1024][1024]
    __bf16* qkvb  = (__bf16*)(ws + (size_t)16 * 1024 * 1024); // 24 MB: [4096][3072]
    __bf16* attb  = (__bf16*)(ws + (size_t)40 * 1024 * 1024); //  8 MB: [4096][1024]
    __bf16* vTb   = xb;  // reuse: xb dead after gemm1, vT born after gemm1

    cvt_bf16_kernel<<<2048, 256, 0, stream>>>(x,    xb,    Mrows * Cd / 8);
    cvt_bf16_kernel<<<1536, 256, 0, stream>>>(Wqkv, wqkvb, 3 * Cd * Cd / 8);
    cvt_bf16_kernel<<<512,  256, 0, stream>>>(Wo,   wob,   Cd * Cd / 8);

    dim3 g1(Mrows / 128, 3 * Cd / 128);   // 32 x 24
    gemm_bt_kernel<true><<<g1, 256, 0, stream>>>(xb, wqkvb, nullptr, qkvb, 3 * Cd, Cd);

    dim3 gt(Mrows / 64, Cd / 64);         // 64 x 16
    transpose_v_kernel<<<gt, 256, 0, stream>>>(qkvb, vTb);

    attn_kernel<<<512, 256, 0, stream>>>(qkvb, vTb, attb);

    dim3 g2(Mrows / 128, Cd / 128);       // 32 x 8
    gemm_bt_kernel<false><<<g2, 256, 0, stream>>>(attb, wob, out, nullptr, Cd, Cd);
}

// Round 5
// 214.748 us; speedup vs baseline: 1.4371x; 1.0329x over previous
//
#include <hip/hip_runtime.h>
#include <hip/hip_bf16.h>
#include <stdint.h>
#include <stddef.h>

// ---------------------------------------------------------------------------
// CausalAttention: x[2,2048,1024] f32, W_QKV[3072,1024], W_O[1024,1024]
// qkv = x @ W_QKV^T ; per-head causal attention ; out = att @ W_O^T
// Matmuls in bf16 MFMA, fp32 accumulate. Attention: swapped 32x32 QK^T,
// in-register softmax (exp2 domain), P packed in-register for PV.
// ---------------------------------------------------------------------------

typedef __attribute__((ext_vector_type(8)))  __bf16   bf16x8;
typedef __attribute__((ext_vector_type(4)))  float    f32x4;
typedef __attribute__((ext_vector_type(16))) float    f32x16;
typedef __attribute__((ext_vector_type(4)))  uint32_t u32x4;

#define AS1(p) ((__attribute__((address_space(1))) void*)(p))
#define AS3(p) ((__attribute__((address_space(3))) void*)(p))

static constexpr int Tq    = 2048;
static constexpr int Cd    = 1024;
static constexpr int Mrows = 2 * Tq;   // 4096

// Q pre-scale: 1/sqrt(64) * log2(e)  (softmax runs in exp2 domain)
#define QSCALE 0.18033688011112042f

// ---------------------------------------------------------------------------
// f32 -> bf16 cast, vectorized 8/thread
// ---------------------------------------------------------------------------
__global__ __launch_bounds__(256) void cvt_bf16_kernel(const float* __restrict__ in,
                                                       __bf16* __restrict__ out, int n8)
{
    int idx    = blockIdx.x * blockDim.x + threadIdx.x;
    int stride = gridDim.x * blockDim.x;
    for (int i = idx; i < n8; i += stride) {
        f32x4 a = ((const f32x4*)in)[i * 2 + 0];
        f32x4 b = ((const f32x4*)in)[i * 2 + 1];
        bf16x8 o;
#pragma unroll
        for (int j = 0; j < 4; ++j) { o[j] = (__bf16)a[j]; o[4 + j] = (__bf16)b[j]; }
        ((bf16x8*)out)[i] = o;
    }
}

// ---------------------------------------------------------------------------
// V transpose: qkv V-part (cols 2048..3071) -> vT[1024][4096]
// ---------------------------------------------------------------------------
__global__ __launch_bounds__(256) void transpose_v_kernel(const __bf16* __restrict__ qkv,
                                                          __bf16* __restrict__ vT)
{
    __shared__ __bf16 tile[64][65];
    const int t   = threadIdx.x;
    const int r0  = blockIdx.x * 64;
    const int hd0 = blockIdx.y * 64;

    {
        const int rr = t >> 2, c16 = (t & 3) * 16;
        const __bf16* src = qkv + (size_t)(r0 + rr) * 3072 + 2048 + hd0 + c16;
        bf16x8 a = *(const bf16x8*)(src);
        bf16x8 b = *(const bf16x8*)(src + 8);
#pragma unroll
        for (int j = 0; j < 8; ++j) { tile[rr][c16 + j] = a[j]; tile[rr][c16 + 8 + j] = b[j]; }
    }
    __syncthreads();
    {
        const int hd_loc = t >> 2, rg = (t & 3) * 16;
        bf16x8 a, b;
#pragma unroll
        for (int j = 0; j < 8; ++j) { a[j] = tile[rg + j][hd_loc]; b[j] = tile[rg + 8 + j][hd_loc]; }
        __bf16* dst = vT + (size_t)(hd0 + hd_loc) * Mrows + r0 + rg;
        *(bf16x8*)(dst)     = a;
        *(bf16x8*)(dst + 8) = b;
    }
}

// ---------------------------------------------------------------------------
// GEMM, B^T layout: C[m][n] = sum_k A[m*K+k] * B[n*K+k]  (m97 structure)
// cols < qcols get scaled by qscale in the epilogue (Q pre-scale for attn).
// ---------------------------------------------------------------------------
template <bool OUT_BF16>
__global__ __launch_bounds__(256) void gemm_bt_kernel(const __bf16* __restrict__ A,
                                                      const __bf16* __restrict__ Bm,
                                                      float* __restrict__ Cf,
                                                      __bf16* __restrict__ Cb,
                                                      int N, int K, int qcols, float qscale)
{
    __shared__ __align__(16) __bf16 As[128 * 64];
    __shared__ __align__(16) __bf16 Bs[128 * 64];

    const int tid = threadIdx.x;
    const int l   = tid & 63;
    const int w   = tid >> 6;
    const int wr  = w >> 1, wc = w & 1;
    const int lo  = l & 15, hi = l >> 4;
    const int m0  = blockIdx.x * 128;
    const int n0  = blockIdx.y * 128;

    f32x4 acc[4][4] = {};

    for (int kk = 0; kk < K; kk += 64) {
#pragma unroll
        for (int i = 0; i < 4; ++i) {
            int s   = i * 256 + tid;
            int row = s >> 3;
            int gg  = (s & 7) ^ (row & 7);
            const __bf16* srcA = A  + (size_t)(m0 + row) * K + kk + gg * 8;
            const __bf16* srcB = Bm + (size_t)(n0 + row) * K + kk + gg * 8;
            __builtin_amdgcn_global_load_lds(AS1(srcA), AS3((char*)As + s * 16), 16, 0, 0);
            __builtin_amdgcn_global_load_lds(AS1(srcB), AS3((char*)Bs + s * 16), 16, 0, 0);
        }
        __syncthreads();

#pragma unroll
        for (int ks = 0; ks < 2; ++ks) {
            bf16x8 af[4], bfr[4];
#pragma unroll
            for (int m = 0; m < 4; ++m) {
                int row = wr * 64 + m * 16 + lo;
                int gl  = (ks * 4 + hi) ^ (row & 7);
                af[m] = *(const bf16x8*)((const char*)As + row * 128 + gl * 16);
            }
#pragma unroll
            for (int n = 0; n < 4; ++n) {
                int row = wc * 64 + n * 16 + lo;
                int gl  = (ks * 4 + hi) ^ (row & 7);
                bfr[n] = *(const bf16x8*)((const char*)Bs + row * 128 + gl * 16);
            }
#pragma unroll
            for (int m = 0; m < 4; ++m)
#pragma unroll
                for (int n = 0; n < 4; ++n)
                    acc[m][n] = __builtin_amdgcn_mfma_f32_16x16x32_bf16(af[m], bfr[n], acc[m][n], 0, 0, 0);
        }
        __syncthreads();
    }

#pragma unroll
    for (int m = 0; m < 4; ++m)
#pragma unroll
        for (int n = 0; n < 4; ++n)
#pragma unroll
            for (int r = 0; r < 4; ++r) {
                int row = m0 + wr * 64 + m * 16 + hi * 4 + r;
                int col = n0 + wc * 64 + n * 16 + lo;
                float v = acc[m][n][r];
                if (col < qcols) v *= qscale;
                if (OUT_BF16) Cb[(size_t)row * N + col] = (__bf16)v;
                else          Cf[(size_t)row * N + col] = v;
            }
}

// ---------------------------------------------------------------------------
// Flash attention, swapped 32x32 structure.
// Grid: 512 blocks (pair j, h, b), 128 threads = 2 waves x 32 q-rows.
// Block q-tile = 64 rows; paired q-tiles {31-j, j} -> 34 kv-iters/block.
// QK^T computed swapped (mfma(K,Q)) -> lane holds S for q=lane&31:
//   k(r) = (r&3) + 8*(r>>2) + 4*(lane>>5)  (sf0: +0, sf1: +32).
// Softmax: in-lane reduce + one shfl_xor(32); defer-max (THR=8, exp2 units).
// P packed to bf16 in-register; 8 shfl_xor(32) word swaps build PV A-frags.
// K / V^T staged dbuf via global_load_lds with XOR-swizzle (conflict-free).
// ---------------------------------------------------------------------------
__global__ __launch_bounds__(128) void attn_kernel(const __bf16* __restrict__ qkv,
                                                   const __bf16* __restrict__ vT,
                                                   __bf16* __restrict__ att)
{
    __shared__ __align__(16) __bf16 Ks[2][64 * 64];
    __shared__ __align__(16) __bf16 Vs[2][64 * 64];

    const int tid = threadIdx.x;
    const int l   = tid & 63;
    const int w   = tid >> 6;          // wave: 0..1
    const int lo5 = l & 31, hi5 = l >> 5;

    const int bid = blockIdx.x;
    const int j   = bid & 15;
    const int h   = (bid >> 4) & 15;
    const int b   = bid >> 8;

    const __bf16* Kbase = qkv + (size_t)b * Tq * 3072 + 1024 + h * 64;   // +k*3072 + d
    const __bf16* Vbase = vT  + (size_t)h * 64 * Mrows + b * Tq;         // +d*4096 + k

    const int qts[2] = {31 - j, j};

    for (int p = 0; p < 2; ++p) {
        const int qt  = qts[p];
        const int qb0 = qt * 64;
        const int nt  = qt + 1;

        // Q fragments (B-operand: col=q=lane&31, k(d) = ds*16 + hi5*8 + jj)
        bf16x8 qf[4];
        {
            const __bf16* Qp = qkv + (size_t)(b * Tq + qb0 + w * 32 + lo5) * 3072 + h * 64 + hi5 * 8;
#pragma unroll
            for (int ds = 0; ds < 4; ++ds) qf[ds] = *(const bf16x8*)(Qp + ds * 16);
        }

        f32x16 o0 = {}, o1 = {};
        float m = -1e30f, lsum = 0.f;

        // prologue: stage tile 0 -> buf 0
#pragma unroll
        for (int i = 0; i < 4; ++i) {
            int s = i * 128 + tid;
            int row = s >> 3, g = (s & 7) ^ (row & 7);
            __builtin_amdgcn_global_load_lds(AS1(Kbase + (size_t)row * 3072 + g * 8),
                                             AS3((char*)Ks[0] + s * 16), 16, 0, 0);
            __builtin_amdgcn_global_load_lds(AS1(Vbase + (size_t)row * Mrows + g * 8),
                                             AS3((char*)Vs[0] + s * 16), 16, 0, 0);
        }
        __syncthreads();

        int cur = 0;
        for (int t = 0; t < nt; ++t) {
            const int k0 = t * 64;

            if (t + 1 < nt) {
                const int kn = k0 + 64;
#pragma unroll
                for (int i = 0; i < 4; ++i) {
                    int s = i * 128 + tid;
                    int row = s >> 3, g = (s & 7) ^ (row & 7);
                    __builtin_amdgcn_global_load_lds(AS1(Kbase + (size_t)(kn + row) * 3072 + g * 8),
                                                     AS3((char*)Ks[cur ^ 1] + s * 16), 16, 0, 0);
                    __builtin_amdgcn_global_load_lds(AS1(Vbase + (size_t)row * Mrows + kn + g * 8),
                                                     AS3((char*)Vs[cur ^ 1] + s * 16), 16, 0, 0);
                }
            }

            // --- S^T = K Q^T (swapped) ---
            f32x16 sf0 = {}, sf1 = {};
#pragma unroll
            for (int ds = 0; ds < 4; ++ds) {
                {
                    int row = lo5;
                    int gl  = (ds * 2 + hi5) ^ (row & 7);
                    bf16x8 kf = *(const bf16x8*)((const char*)Ks[cur] + row * 128 + gl * 16);
                    sf0 = __builtin_amdgcn_mfma_f32_32x32x16_bf16(kf, qf[ds], sf0, 0, 0, 0);
                }
                {
                    int row = 32 + lo5;
                    int gl  = (ds * 2 + hi5) ^ (row & 7);
                    bf16x8 kf = *(const bf16x8*)((const char*)Ks[cur] + row * 128 + gl * 16);
                    sf1 = __builtin_amdgcn_mfma_f32_32x32x16_bf16(kf, qf[ds], sf1, 0, 0, 0);
                }
            }

            // --- causal mask (diagonal tile only; k0 == qb0 there) ---
            if (t == qt) {
                const int ql = w * 32 + lo5;
#pragma unroll
                for (int r = 0; r < 16; ++r) {
                    int kc = (r & 3) + 8 * (r >> 2) + 4 * hi5;
                    if (kc      > ql) sf0[r] = -1e30f;
                    if (kc + 32 > ql) sf1[r] = -1e30f;
                }
            }

            // --- row max: in-lane tree + one cross-half swap ---
            float pmh = fmaxf(sf0[0], sf0[1]);
#pragma unroll
            for (int r = 2; r < 16; ++r) pmh = fmaxf(pmh, sf0[r]);
#pragma unroll
            for (int r = 0; r < 16; ++r) pmh = fmaxf(pmh, sf1[r]);
            float pm = fmaxf(pmh, __shfl_xor(pmh, 32));

            // --- defer-max: rescale only on significant growth ---
            if (__any(pm > m + 8.0f)) {
                float mnew = fmaxf(m, pm);
                float fac  = exp2f(m - mnew);
                m = mnew;
                lsum *= fac;
#pragma unroll
                for (int r = 0; r < 16; ++r) {
                    int qreg = (r & 3) + 8 * (r >> 2) + 4 * hi5;
                    float fr = __shfl(fac, qreg);
                    o0[r] *= fr;
                    o1[r] *= fr;
                }
            }

            // --- P = exp2(S - m), pack to bf16 words, exchange, PV ---
            float psum = 0.f;
#pragma unroll
            for (int kb = 0; kb < 2; ++kb) {
                uint32_t W[8];
#pragma unroll
                for (int wd = 0; wd < 8; ++wd) {
                    float sa = (kb == 0) ? sf0[2 * wd]     : sf1[2 * wd];
                    float sb = (kb == 0) ? sf0[2 * wd + 1] : sf1[2 * wd + 1];
                    float pa = exp2f(sa - m);
                    float pb = exp2f(sb - m);
                    __bf16 ba = (__bf16)pa, bb = (__bf16)pb;
                    psum += (float)ba + (float)bb;      // sum the rounded values (matches numerator)
                    W[wd] = (uint32_t)__builtin_bit_cast(uint16_t, ba)
                          | ((uint32_t)__builtin_bit_cast(uint16_t, bb) << 16);
                }
                // cross-half word exchange (partner lane l^32 has same q)
                uint32_t Za = __shfl_xor(hi5 ? W[0] : W[2], 32);
                uint32_t Zb = __shfl_xor(hi5 ? W[1] : W[3], 32);
                uint32_t Zc = __shfl_xor(hi5 ? W[4] : W[6], 32);
                uint32_t Zd = __shfl_xor(hi5 ? W[5] : W[7], 32);

                // kstep = kb*2 + 0
                {
                    u32x4 fw = { hi5 ? Za : W[0], hi5 ? Zb : W[1],
                                 hi5 ? W[2] : Za, hi5 ? W[3] : Zb };
                    bf16x8 pa = __builtin_bit_cast(bf16x8, fw);
                    const int kstep = kb * 2;
                    {
                        int row = lo5;
                        int gl  = (kstep * 2 + hi5) ^ (row & 7);
                        bf16x8 vb = *(const bf16x8*)((const char*)Vs[cur] + row * 128 + gl * 16);
                        o0 = __builtin_amdgcn_mfma_f32_32x32x16_bf16(pa, vb, o0, 0, 0, 0);
                    }
                    {
                        int row = 32 + lo5;
                        int gl  = (kstep * 2 + hi5) ^ (row & 7);
                        bf16x8 vb = *(const bf16x8*)((const char*)Vs[cur] + row * 128 + gl * 16);
                        o1 = __builtin_amdgcn_mfma_f32_32x32x16_bf16(pa, vb, o1, 0, 0, 0);
                    }
                }
                // kstep = kb*2 + 1
                {
                    u32x4 fw = { hi5 ? Zc : W[4], hi5 ? Zd : W[5],
                                 hi5 ? W[6] : Zc, hi5 ? W[7] : Zd };
                    bf16x8 pa = __builtin_bit_cast(bf16x8, fw);
                    const int kstep = kb * 2 + 1;
                    {
                        int row = lo5;
                        int gl  = (kstep * 2 + hi5) ^ (row & 7);
                        bf16x8 vb = *(const bf16x8*)((const char*)Vs[cur] + row * 128 + gl * 16);
                        o0 = __builtin_amdgcn_mfma_f32_32x32x16_bf16(pa, vb, o0, 0, 0, 0);
                    }
                    {
                        int row = 32 + lo5;
                        int gl  = (kstep * 2 + hi5) ^ (row & 7);
                        bf16x8 vb = *(const bf16x8*)((const char*)Vs[cur] + row * 128 + gl * 16);
                        o1 = __builtin_amdgcn_mfma_f32_32x32x16_bf16(pa, vb, o1, 0, 0, 0);
                    }
                }
            }
            psum += __shfl_xor(psum, 32);   // full row sum (both k-halves)
            lsum += psum;

            __syncthreads();   // buf[cur^1] staged; protects buf reuse
            cur ^= 1;
        }

        // --- normalize + write att[4096][1024] ---
        float linv = 1.0f / lsum;
#pragma unroll
        for (int r = 0; r < 16; ++r) {
            int   qreg = (r & 3) + 8 * (r >> 2) + 4 * hi5;
            float lr   = __shfl(linv, qreg);
            int   rowg = b * Tq + qb0 + w * 32 + qreg;
            att[(size_t)rowg * Cd + h * 64 + lo5]      = (__bf16)(o0[r] * lr);
            att[(size_t)rowg * Cd + h * 64 + 32 + lo5] = (__bf16)(o1[r] * lr);
        }
    }
}

// ---------------------------------------------------------------------------
// Launch
// ---------------------------------------------------------------------------
extern "C" void kernel_launch(void* const* d_in, const int* in_sizes, int n_in,
                              void* d_out, int out_size, void* d_ws, size_t ws_size,
                              hipStream_t stream)
{
    (void)in_sizes; (void)n_in; (void)out_size; (void)ws_size;

    const float* x    = (const float*)d_in[0];
    const float* Wqkv = (const float*)d_in[1];
    const float* Wo   = (const float*)d_in[2];
    float*       out  = (float*)d_out;

    char* ws = (char*)d_ws;
    __bf16* xb    = (__bf16*)(ws);                            //  8 MB: [4096][1024]
    __bf16* wqkvb = (__bf16*)(ws + (size_t)8  * 1024 * 1024); //  6 MB: [3072][1024]
    __bf16* wob   = (__bf16*)(ws + (size_t)14 * 1024 * 1024); //  2 MB: [1024][1024]
    __bf16* qkvb  = (__bf16*)(ws + (size_t)16 * 1024 * 1024); // 24 MB: [4096][3072]
    __bf16* attb  = (__bf16*)(ws + (size_t)40 * 1024 * 1024); //  8 MB: [4096][1024]
    __bf16* vTb   = xb;  // reuse: xb dead after gemm1

    cvt_bf16_kernel<<<2048, 256, 0, stream>>>(x,    xb,    Mrows * Cd / 8);
    cvt_bf16_kernel<<<1536, 256, 0, stream>>>(Wqkv, wqkvb, 3 * Cd * Cd / 8);
    cvt_bf16_kernel<<<512,  256, 0, stream>>>(Wo,   wob,   Cd * Cd / 8);

    dim3 g1(Mrows / 128, 3 * Cd / 128);   // 32 x 24
    gemm_bt_kernel<true><<<g1, 256, 0, stream>>>(xb, wqkvb, nullptr, qkvb, 3 * Cd, Cd,
                                                 1024, QSCALE);   // pre-scale Q columns

    dim3 gt(Mrows / 64, Cd / 64);         // 64 x 16
    transpose_v_kernel<<<gt, 256, 0, stream>>>(qkvb, vTb);

    attn_kernel<<<512, 128, 0, stream>>>(qkvb, vTb, attb);

    dim3 g2(Mrows / 128, Cd / 128);       // 32 x 8
    gemm_bt_kernel<false><<<g2, 256, 0, stream>>>(attb, wob, out, nullptr, Cd, Cd,
                                                  0, 1.0f);
}

// Round 6
// 206.179 us; speedup vs baseline: 1.4968x; 1.0416x over previous
//
#include <hip/hip_runtime.h>
#include <hip/hip_bf16.h>
#include <stdint.h>
#include <stddef.h>

// ---------------------------------------------------------------------------
// CausalAttention: x[2,2048,1024] f32, W_QKV[3072,1024], W_O[1024,1024]
// qkv = x @ W_QKV^T ; per-head causal attention ; out = att @ W_O^T
// Matmuls in bf16 MFMA, fp32 accumulate. Attention: swapped 32x32 QK^T,
// in-register softmax (exp2 domain), P packed in-register for PV,
// row-sums via MFMA-with-ones (register-indexed lsum, shuffle-free epilogue).
// ---------------------------------------------------------------------------

typedef __attribute__((ext_vector_type(8)))  __bf16   bf16x8;
typedef __attribute__((ext_vector_type(4)))  float    f32x4;
typedef __attribute__((ext_vector_type(16))) float    f32x16;
typedef __attribute__((ext_vector_type(4)))  uint32_t u32x4;

#define AS1(p) ((__attribute__((address_space(1))) void*)(p))
#define AS3(p) ((__attribute__((address_space(3))) void*)(p))

static constexpr int Tq    = 2048;
static constexpr int Cd    = 1024;
static constexpr int Mrows = 2 * Tq;   // 4096

// Q pre-scale: 1/sqrt(64) * log2(e)  (softmax runs in exp2 domain)
#define QSCALE 0.18033688011112042f

// ---------------------------------------------------------------------------
// f32 -> bf16 cast, vectorized 8/thread
// ---------------------------------------------------------------------------
__global__ __launch_bounds__(256) void cvt_bf16_kernel(const float* __restrict__ in,
                                                       __bf16* __restrict__ out, int n8)
{
    int idx    = blockIdx.x * blockDim.x + threadIdx.x;
    int stride = gridDim.x * blockDim.x;
    for (int i = idx; i < n8; i += stride) {
        f32x4 a = ((const f32x4*)in)[i * 2 + 0];
        f32x4 b = ((const f32x4*)in)[i * 2 + 1];
        bf16x8 o;
#pragma unroll
        for (int j = 0; j < 4; ++j) { o[j] = (__bf16)a[j]; o[4 + j] = (__bf16)b[j]; }
        ((bf16x8*)out)[i] = o;
    }
}

// ---------------------------------------------------------------------------
// V transpose: qkv V-part (cols 2048..3071) -> vT[1024][4096]
// ---------------------------------------------------------------------------
__global__ __launch_bounds__(256) void transpose_v_kernel(const __bf16* __restrict__ qkv,
                                                          __bf16* __restrict__ vT)
{
    __shared__ __bf16 tile[64][65];
    const int t   = threadIdx.x;
    const int r0  = blockIdx.x * 64;
    const int hd0 = blockIdx.y * 64;

    {
        const int rr = t >> 2, c16 = (t & 3) * 16;
        const __bf16* src = qkv + (size_t)(r0 + rr) * 3072 + 2048 + hd0 + c16;
        bf16x8 a = *(const bf16x8*)(src);
        bf16x8 b = *(const bf16x8*)(src + 8);
#pragma unroll
        for (int j = 0; j < 8; ++j) { tile[rr][c16 + j] = a[j]; tile[rr][c16 + 8 + j] = b[j]; }
    }
    __syncthreads();
    {
        const int hd_loc = t >> 2, rg = (t & 3) * 16;
        bf16x8 a, b;
#pragma unroll
        for (int j = 0; j < 8; ++j) { a[j] = tile[rg + j][hd_loc]; b[j] = tile[rg + 8 + j][hd_loc]; }
        __bf16* dst = vT + (size_t)(hd0 + hd_loc) * Mrows + r0 + rg;
        *(bf16x8*)(dst)     = a;
        *(bf16x8*)(dst + 8) = b;
    }
}

// ---------------------------------------------------------------------------
// GEMM, B^T layout: C[m][n] = sum_k A[m*K+k] * B[n*K+k]  (m97 structure)
// cols < qcols get scaled by qscale in the epilogue (Q pre-scale for attn).
// ---------------------------------------------------------------------------
template <bool OUT_BF16>
__global__ __launch_bounds__(256) void gemm_bt_kernel(const __bf16* __restrict__ A,
                                                      const __bf16* __restrict__ Bm,
                                                      float* __restrict__ Cf,
                                                      __bf16* __restrict__ Cb,
                                                      int N, int K, int qcols, float qscale)
{
    __shared__ __align__(16) __bf16 As[128 * 64];
    __shared__ __align__(16) __bf16 Bs[128 * 64];

    const int tid = threadIdx.x;
    const int l   = tid & 63;
    const int w   = tid >> 6;
    const int wr  = w >> 1, wc = w & 1;
    const int lo  = l & 15, hi = l >> 4;
    const int m0  = blockIdx.x * 128;
    const int n0  = blockIdx.y * 128;

    f32x4 acc[4][4] = {};

    for (int kk = 0; kk < K; kk += 64) {
#pragma unroll
        for (int i = 0; i < 4; ++i) {
            int s   = i * 256 + tid;
            int row = s >> 3;
            int gg  = (s & 7) ^ (row & 7);
            const __bf16* srcA = A  + (size_t)(m0 + row) * K + kk + gg * 8;
            const __bf16* srcB = Bm + (size_t)(n0 + row) * K + kk + gg * 8;
            __builtin_amdgcn_global_load_lds(AS1(srcA), AS3((char*)As + s * 16), 16, 0, 0);
            __builtin_amdgcn_global_load_lds(AS1(srcB), AS3((char*)Bs + s * 16), 16, 0, 0);
        }
        __syncthreads();

#pragma unroll
        for (int ks = 0; ks < 2; ++ks) {
            bf16x8 af[4], bfr[4];
#pragma unroll
            for (int m = 0; m < 4; ++m) {
                int row = wr * 64 + m * 16 + lo;
                int gl  = (ks * 4 + hi) ^ (row & 7);
                af[m] = *(const bf16x8*)((const char*)As + row * 128 + gl * 16);
            }
#pragma unroll
            for (int n = 0; n < 4; ++n) {
                int row = wc * 64 + n * 16 + lo;
                int gl  = (ks * 4 + hi) ^ (row & 7);
                bfr[n] = *(const bf16x8*)((const char*)Bs + row * 128 + gl * 16);
            }
#pragma unroll
            for (int m = 0; m < 4; ++m)
#pragma unroll
                for (int n = 0; n < 4; ++n)
                    acc[m][n] = __builtin_amdgcn_mfma_f32_16x16x32_bf16(af[m], bfr[n], acc[m][n], 0, 0, 0);
        }
        __syncthreads();
    }

#pragma unroll
    for (int m = 0; m < 4; ++m)
#pragma unroll
        for (int n = 0; n < 4; ++n)
#pragma unroll
            for (int r = 0; r < 4; ++r) {
                int row = m0 + wr * 64 + m * 16 + hi * 4 + r;
                int col = n0 + wc * 64 + n * 16 + lo;
                float v = acc[m][n][r];
                if (col < qcols) v *= qscale;
                if (OUT_BF16) Cb[(size_t)row * N + col] = (__bf16)v;
                else          Cf[(size_t)row * N + col] = v;
            }
}

// ---------------------------------------------------------------------------
// Flash attention, swapped 32x32 structure, occupancy-first layout.
// Grid: 1024 blocks x 128 threads (2 waves x 32 q-rows = one 64-row q-tile).
// Snake qt mapping: c=bid>>8, g=(bid>>5)&7 -> qt {31-g,16+g,15-g,g}: under
// round-robin dispatch each CU's 4 blocks sum to exactly 66 iterations,
// longest blocks dispatch first. Blocks sharing (b,h) are bids == bh (mod 32)
// -> same XCD -> K/V stream stays in one XCD L2.
// lsum via MFMA-with-ones: register-indexed, shuffle-free normalize.
// exp2/rcp via __builtin_amdgcn_* (single v_exp_f32 / v_rcp_f32).
// ---------------------------------------------------------------------------
__global__ __launch_bounds__(128) void attn_kernel(const __bf16* __restrict__ qkv,
                                                   const __bf16* __restrict__ vT,
                                                   __bf16* __restrict__ att)
{
    __shared__ __align__(16) __bf16 Ks[2][64 * 64];
    __shared__ __align__(16) __bf16 Vs[2][64 * 64];

    const int tid = threadIdx.x;
    const int l   = tid & 63;
    const int w   = tid >> 6;          // wave: 0..1
    const int lo5 = l & 31, hi5 = l >> 5;

    const int bid = blockIdx.x;
    const int g   = (bid >> 5) & 7;
    const int c   = bid >> 8;          // 0..3
    const int qt  = (c & 1) ? (16 - ((c >> 1) << 4) + g)    // c=1:16+g  c=3:g
                            : (31 - ((c >> 1) << 4) - g);   // c=0:31-g  c=2:15-g
    const int bh  = bid & 31;
    const int h   = bh & 15;
    const int b   = bh >> 4;

    const __bf16* Kbase = qkv + (size_t)b * Tq * 3072 + 1024 + h * 64;   // +k*3072 + d
    const __bf16* Vbase = vT  + (size_t)h * 64 * Mrows + b * Tq;         // +d*4096 + k

    const int qb0 = qt * 64;
    const int nt  = qt + 1;

    // ones fragment for MFMA row-sum (B-operand, any layout: all 1.0)
    bf16x8 onesf;
#pragma unroll
    for (int jj = 0; jj < 8; ++jj) onesf[jj] = (__bf16)1.0f;

    // Q fragments (B-operand: col=q=lane&31, k(d) = ds*16 + hi5*8 + jj)
    bf16x8 qf[4];
    {
        const __bf16* Qp = qkv + (size_t)(b * Tq + qb0 + w * 32 + lo5) * 3072 + h * 64 + hi5 * 8;
#pragma unroll
        for (int ds = 0; ds < 4; ++ds) qf[ds] = *(const bf16x8*)(Qp + ds * 16);
    }

    f32x16 o0 = {}, o1 = {}, ls = {};
    float m = -1e30f;

    // prologue: stage tile 0 -> buf 0
#pragma unroll
    for (int i = 0; i < 4; ++i) {
        int s = i * 128 + tid;
        int row = s >> 3, gg = (s & 7) ^ (row & 7);
        __builtin_amdgcn_global_load_lds(AS1(Kbase + (size_t)row * 3072 + gg * 8),
                                         AS3((char*)Ks[0] + s * 16), 16, 0, 0);
        __builtin_amdgcn_global_load_lds(AS1(Vbase + (size_t)row * Mrows + gg * 8),
                                         AS3((char*)Vs[0] + s * 16), 16, 0, 0);
    }
    __syncthreads();

    int cur = 0;
    for (int t = 0; t < nt; ++t) {
        // stage next tile into buf cur^1 (overlaps with compute below)
        if (t + 1 < nt) {
            const int kn = (t + 1) * 64;
#pragma unroll
            for (int i = 0; i < 4; ++i) {
                int s = i * 128 + tid;
                int row = s >> 3, gg = (s & 7) ^ (row & 7);
                __builtin_amdgcn_global_load_lds(AS1(Kbase + (size_t)(kn + row) * 3072 + gg * 8),
                                                 AS3((char*)Ks[cur ^ 1] + s * 16), 16, 0, 0);
                __builtin_amdgcn_global_load_lds(AS1(Vbase + (size_t)row * Mrows + kn + gg * 8),
                                                 AS3((char*)Vs[cur ^ 1] + s * 16), 16, 0, 0);
            }
        }

        // --- S^T = K Q^T (swapped): lane holds S for q=lane&31,
        //     k(r) = (r&3)+8*(r>>2)+4*hi5 (sf0: +0, sf1: +32) ---
        f32x16 sf0 = {}, sf1 = {};
        __builtin_amdgcn_s_setprio(1);
#pragma unroll
        for (int ds = 0; ds < 4; ++ds) {
            {
                int row = lo5;
                int gl  = (ds * 2 + hi5) ^ (row & 7);
                bf16x8 kf = *(const bf16x8*)((const char*)Ks[cur] + row * 128 + gl * 16);
                sf0 = __builtin_amdgcn_mfma_f32_32x32x16_bf16(kf, qf[ds], sf0, 0, 0, 0);
            }
            {
                int row = 32 + lo5;
                int gl  = (ds * 2 + hi5) ^ (row & 7);
                bf16x8 kf = *(const bf16x8*)((const char*)Ks[cur] + row * 128 + gl * 16);
                sf1 = __builtin_amdgcn_mfma_f32_32x32x16_bf16(kf, qf[ds], sf1, 0, 0, 0);
            }
        }
        __builtin_amdgcn_s_setprio(0);

        // --- causal mask (diagonal tile only) ---
        if (t == qt) {
            const int ql = w * 32 + lo5;
#pragma unroll
            for (int r = 0; r < 16; ++r) {
                int kc = (r & 3) + 8 * (r >> 2) + 4 * hi5;
                if (kc      > ql) sf0[r] = -1e30f;
                if (kc + 32 > ql) sf1[r] = -1e30f;
            }
        }

        // --- row max: max3-friendly tree + one cross-half swap ---
        float t0 = fmaxf(sf0[0],  fmaxf(sf0[1],  sf0[2]));
        float t1 = fmaxf(sf0[3],  fmaxf(sf0[4],  sf0[5]));
        float t2 = fmaxf(sf0[6],  fmaxf(sf0[7],  sf0[8]));
        float t3 = fmaxf(sf0[9],  fmaxf(sf0[10], sf0[11]));
        float t4 = fmaxf(sf0[12], fmaxf(sf0[13], sf0[14]));
        float t5 = fmaxf(sf1[0],  fmaxf(sf1[1],  sf1[2]));
        float t6 = fmaxf(sf1[3],  fmaxf(sf1[4],  sf1[5]));
        float t7 = fmaxf(sf1[6],  fmaxf(sf1[7],  sf1[8]));
        float t8 = fmaxf(sf1[9],  fmaxf(sf1[10], sf1[11]));
        float t9 = fmaxf(sf1[12], fmaxf(sf1[13], sf1[14]));
        float u0 = fmaxf(t0, fmaxf(t1, t2));
        float u1 = fmaxf(t3, fmaxf(t4, sf0[15]));
        float u2 = fmaxf(t5, fmaxf(t6, t7));
        float u3 = fmaxf(t8, fmaxf(t9, sf1[15]));
        float pmh = fmaxf(fmaxf(u0, u1), fmaxf(u2, u3));
        float pm  = fmaxf(pmh, __shfl_xor(pmh, 32));

        // --- defer-max: rescale only on significant growth (THR=8 in log2) ---
        if (__any(pm > m + 8.0f)) {
            float mnew = fmaxf(m, pm);
            float fac  = __builtin_amdgcn_exp2f(m - mnew);
            m = mnew;
#pragma unroll
            for (int r = 0; r < 16; ++r) {
                int qreg = (r & 3) + 8 * (r >> 2) + 4 * hi5;
                float fr = __shfl(fac, qreg);
                o0[r] *= fr;
                o1[r] *= fr;
                ls[r] *= fr;
            }
        }

        // --- P = exp2(S - m), pack to bf16 words, exchange, PV + lsum MFMA ---
        __builtin_amdgcn_s_setprio(1);
#pragma unroll
        for (int kb = 0; kb < 2; ++kb) {
            uint32_t W[8];
#pragma unroll
            for (int wd = 0; wd < 8; ++wd) {
                float sa = (kb == 0) ? sf0[2 * wd]     : sf1[2 * wd];
                float sb = (kb == 0) ? sf0[2 * wd + 1] : sf1[2 * wd + 1];
                __bf16 ba = (__bf16)__builtin_amdgcn_exp2f(sa - m);
                __bf16 bb = (__bf16)__builtin_amdgcn_exp2f(sb - m);
                W[wd] = (uint32_t)__builtin_bit_cast(uint16_t, ba)
                      | ((uint32_t)__builtin_bit_cast(uint16_t, bb) << 16);
            }
            // cross-half word exchange (partner lane l^32 has same q)
            uint32_t Za = __shfl_xor(hi5 ? W[0] : W[2], 32);
            uint32_t Zb = __shfl_xor(hi5 ? W[1] : W[3], 32);
            uint32_t Zc = __shfl_xor(hi5 ? W[4] : W[6], 32);
            uint32_t Zd = __shfl_xor(hi5 ? W[5] : W[7], 32);

            // kstep = kb*2 + 0
            {
                u32x4 fw = { hi5 ? Za : W[0], hi5 ? Zb : W[1],
                             hi5 ? W[2] : Za, hi5 ? W[3] : Zb };
                bf16x8 pa = __builtin_bit_cast(bf16x8, fw);
                const int kstep = kb * 2;
                {
                    int row = lo5;
                    int gl  = (kstep * 2 + hi5) ^ (row & 7);
                    bf16x8 vb = *(const bf16x8*)((const char*)Vs[cur] + row * 128 + gl * 16);
                    o0 = __builtin_amdgcn_mfma_f32_32x32x16_bf16(pa, vb, o0, 0, 0, 0);
                }
                {
                    int row = 32 + lo5;
                    int gl  = (kstep * 2 + hi5) ^ (row & 7);
                    bf16x8 vb = *(const bf16x8*)((const char*)Vs[cur] + row * 128 + gl * 16);
                    o1 = __builtin_amdgcn_mfma_f32_32x32x16_bf16(pa, vb, o1, 0, 0, 0);
                }
                ls = __builtin_amdgcn_mfma_f32_32x32x16_bf16(pa, onesf, ls, 0, 0, 0);
            }
            // kstep = kb*2 + 1
            {
                u32x4 fw = { hi5 ? Zc : W[4], hi5 ? Zd : W[5],
                             hi5 ? W[6] : Zc, hi5 ? W[7] : Zd };
                bf16x8 pa = __builtin_bit_cast(bf16x8, fw);
                const int kstep = kb * 2 + 1;
                {
                    int row = lo5;
                    int gl  = (kstep * 2 + hi5) ^ (row & 7);
                    bf16x8 vb = *(const bf16x8*)((const char*)Vs[cur] + row * 128 + gl * 16);
                    o0 = __builtin_amdgcn_mfma_f32_32x32x16_bf16(pa, vb, o0, 0, 0, 0);
                }
                {
                    int row = 32 + lo5;
                    int gl  = (kstep * 2 + hi5) ^ (row & 7);
                    bf16x8 vb = *(const bf16x8*)((const char*)Vs[cur] + row * 128 + gl * 16);
                    o1 = __builtin_amdgcn_mfma_f32_32x32x16_bf16(pa, vb, o1, 0, 0, 0);
                }
                ls = __builtin_amdgcn_mfma_f32_32x32x16_bf16(pa, onesf, ls, 0, 0, 0);
            }
        }
        __builtin_amdgcn_s_setprio(0);

        __syncthreads();   // buf[cur^1] staged; protects buf reuse
        cur ^= 1;
    }

    // --- normalize + write att[4096][1024] (ls is register-indexed: no shfl) ---
#pragma unroll
    for (int r = 0; r < 16; ++r) {
        float lr   = __builtin_amdgcn_rcpf(ls[r]);
        int   qreg = (r & 3) + 8 * (r >> 2) + 4 * hi5;
        int   rowg = b * Tq + qb0 + w * 32 + qreg;
        att[(size_t)rowg * Cd + h * 64 + lo5]      = (__bf16)(o0[r] * lr);
        att[(size_t)rowg * Cd + h * 64 + 32 + lo5] = (__bf16)(o1[r] * lr);
    }
}

// ---------------------------------------------------------------------------
// Launch
// ---------------------------------------------------------------------------
extern "C" void kernel_launch(void* const* d_in, const int* in_sizes, int n_in,
                              void* d_out, int out_size, void* d_ws, size_t ws_size,
                              hipStream_t stream)
{
    (void)in_sizes; (void)n_in; (void)out_size; (void)ws_size;

    const float* x    = (const float*)d_in[0];
    const float* Wqkv = (const float*)d_in[1];
    const float* Wo   = (const float*)d_in[2];
    float*       out  = (float*)d_out;

    char* ws = (char*)d_ws;
    __bf16* xb    = (__bf16*)(ws);                            //  8 MB: [4096][1024]
    __bf16* wqkvb = (__bf16*)(ws + (size_t)8  * 1024 * 1024); //  6 MB: [3072][1024]
    __bf16* wob   = (__bf16*)(ws + (size_t)14 * 1024 * 1024); //  2 MB: [1024][1024]
    __bf16* qkvb  = (__bf16*)(ws + (size_t)16 * 1024 * 1024); // 24 MB: [4096][3072]
    __bf16* attb  = (__bf16*)(ws + (size_t)40 * 1024 * 1024); //  8 MB: [4096][1024]
    __bf16* vTb   = xb;  // reuse: xb dead after gemm1

    cvt_bf16_kernel<<<2048, 256, 0, stream>>>(x,    xb,    Mrows * Cd / 8);
    cvt_bf16_kernel<<<1536, 256, 0, stream>>>(Wqkv, wqkvb, 3 * Cd * Cd / 8);
    cvt_bf16_kernel<<<512,  256, 0, stream>>>(Wo,   wob,   Cd * Cd / 8);

    dim3 g1(Mrows / 128, 3 * Cd / 128);   // 32 x 24
    gemm_bt_kernel<true><<<g1, 256, 0, stream>>>(xb, wqkvb, nullptr, qkvb, 3 * Cd, Cd,
                                                 1024, QSCALE);   // pre-scale Q columns

    dim3 gt(Mrows / 64, Cd / 64);         // 64 x 16
    transpose_v_kernel<<<gt, 256, 0, stream>>>(qkvb, vTb);

    attn_kernel<<<1024, 128, 0, stream>>>(qkvb, vTb, attb);

    dim3 g2(Mrows / 128, Cd / 128);       // 32 x 8
    gemm_bt_kernel<false><<<g2, 256, 0, stream>>>(attb, wob, out, nullptr, Cd, Cd,
                                                  0, 1.0f);
}